// Round 4
// baseline (99.317 us; speedup 1.0000x reference)
//
#include <hip/hip_runtime.h>

#define D_ROWS 136
#define B_COLS 131072            // 2^17
#define NTHREADS 256
#define ROWS_PER_CHUNK 8
#define ROW_CHUNKS (D_ROWS / ROWS_PER_CHUNK)   // 17
#define CQ_TOTAL (B_COLS / 4)                  // 32768 column-quads
#define CQ_BLOCKS (CQ_TOTAL / NTHREADS)        // 128
#define K2_BLOCKS (CQ_BLOCKS * ROW_CHUNKS)     // 2176
#define NACC 64                                 // partial-accumulator slots

// ws layout: acc[NACC] doubles, then ticket (unsigned int)
// ---------------------------------------------------------------------------
// Kernel 1: per-column weight + zero the accumulator slots / ticket.
// 1 column per thread -> 512 blocks (better ramp than 128).
// ---------------------------------------------------------------------------
__global__ __launch_bounds__(NTHREADS) void weight_kernel(
    const float* __restrict__ ea,        // [3][B]
    const int*   __restrict__ attr,      // [6][B]
    const float* __restrict__ attr_num,  // [6]
    float*       __restrict__ weight,    // [B]
    double*      __restrict__ acc,
    unsigned int* __restrict__ ticket)
{
    int b = blockIdx.x * blockDim.x + threadIdx.x;

    if (blockIdx.x == 0) {
        if (threadIdx.x < NACC) acc[threadIdx.x] = 0.0;
        if (threadIdx.x == NACC) *ticket = 0u;
    }

    if (b >= B_COLS) return;

    float total = attr_num[0] + attr_num[1] + attr_num[2] +
                  attr_num[3] + attr_num[4] + attr_num[5];

    float aw = 0.f;
#pragma unroll
    for (int j = 0; j < 6; ++j) {
        int a = attr[j * B_COLS + b];
        aw += (a == 1) ? (total / attr_num[j]) : 0.f;
    }

    float angw = 0.f;
#pragma unroll
    for (int j = 0; j < 3; ++j)
        angw += 1.f - cosf(ea[j * B_COLS + b]);

    weight[b] = aw * angw;
}

// ---------------------------------------------------------------------------
// Kernel 2: fused weighted-SSE + last-block final reduce (no 3rd kernel).
// Each thread: one column-quad x 8 rows. All 17 loads issued BEFORE any use;
// the asm memory barrier stops the scheduler from sinking loads to uses.
// ---------------------------------------------------------------------------
__global__ __launch_bounds__(NTHREADS) void mse_kernel(
    const float4* __restrict__ inp,
    const float4* __restrict__ label,
    const float4* __restrict__ weight4,
    double*       __restrict__ acc,
    unsigned int* __restrict__ ticket,
    float*        __restrict__ out)
{
    const int cq  = blockIdx.x * blockDim.x + threadIdx.x;   // 0..32767
    const int idx = blockIdx.y * ROWS_PER_CHUNK * CQ_TOTAL + cq;

    float4 w = weight4[cq];
    float4 av[ROWS_PER_CHUNK];
    float4 lv[ROWS_PER_CHUNK];
#pragma unroll
    for (int r = 0; r < ROWS_PER_CHUNK; ++r)
        av[r] = inp[idx + r * CQ_TOTAL];
#pragma unroll
    for (int r = 0; r < ROWS_PER_CHUNK; ++r)
        lv[r] = label[idx + r * CQ_TOTAL];
    asm volatile("" ::: "memory");   // keep all 17 loads issued up-front

    float acc_f = 0.f;
#pragma unroll
    for (int r = 0; r < ROWS_PER_CHUNK; ++r) {
        float dx = av[r].x - lv[r].x;
        float dy = av[r].y - lv[r].y;
        float dz = av[r].z - lv[r].z;
        float dw = av[r].w - lv[r].w;
        acc_f += w.x * dx * dx + w.y * dy * dy + w.z * dz * dz + w.w * dw * dw;
    }

    // 64-lane wave shuffle reduce
    for (int off = 32; off > 0; off >>= 1)
        acc_f += __shfl_down(acc_f, off, 64);

    __shared__ double sw[NTHREADS / 64];
    int lane = threadIdx.x & 63;
    int wid  = threadIdx.x >> 6;
    if (lane == 0) sw[wid] = (double)acc_f;
    __syncthreads();

    if (threadIdx.x == 0) {
        double s = sw[0] + sw[1] + sw[2] + sw[3];
        int bid = blockIdx.y * gridDim.x + blockIdx.x;
        atomicAdd(&acc[bid & (NACC - 1)], s);
        __threadfence();
        unsigned int old = atomicAdd(ticket, 1u);
        if (old == K2_BLOCKS - 1) {
            // last block: all partials are in; reduce the 64 slots
            __threadfence();
            double t = 0.0;
#pragma unroll
            for (int i = 0; i < NACC; ++i)
                t += __hip_atomic_load(&acc[i], __ATOMIC_RELAXED,
                                       __HIP_MEMORY_SCOPE_AGENT);
            out[0] = (float)(t / ((double)D_ROWS * (double)B_COLS));
        }
    }
}

// ---------------------------------------------------------------------------
extern "C" void kernel_launch(void* const* d_in, const int* in_sizes, int n_in,
                              void* d_out, int out_size, void* d_ws, size_t ws_size,
                              hipStream_t stream) {
    const float* inp      = (const float*)d_in[0];   // [D][B]
    const float* label    = (const float*)d_in[1];   // [D][B]
    const float* ea       = (const float*)d_in[2];   // [3][B]
    const int*   attr     = (const int*)d_in[3];     // [6][B]
    const float* attr_num = (const float*)d_in[4];   // [6]
    float* out = (float*)d_out;

    // ws layout: acc[NACC] doubles | ticket | weight[B] floats
    double*       acc    = (double*)d_ws;
    unsigned int* ticket = (unsigned int*)((char*)d_ws + NACC * sizeof(double));
    float*        weight = (float*)((char*)d_ws + NACC * sizeof(double) + 256);

    weight_kernel<<<B_COLS / NTHREADS, NTHREADS, 0, stream>>>(
        ea, attr, attr_num, weight, acc, ticket);

    mse_kernel<<<dim3(CQ_BLOCKS, ROW_CHUNKS), NTHREADS, 0, stream>>>(
        (const float4*)inp, (const float4*)label, (const float4*)weight,
        acc, ticket, out);
}

// Round 5
// 34.080 us; speedup vs baseline: 2.9143x; 2.9143x over previous
//
#include <hip/hip_runtime.h>

#define D_ROWS 136
#define B_COLS 131072            // 2^17
#define NTHREADS 256
#define ROWS_PER_CHUNK 8
#define ROW_CHUNKS (D_ROWS / ROWS_PER_CHUNK)   // 17
#define CQ_TOTAL (B_COLS / 4)                  // 32768 column-quads
#define CQ_BLOCKS (CQ_TOTAL / NTHREADS)        // 128
#define NPARTIALS (CQ_BLOCKS * ROW_CHUNKS)     // 2176

typedef float f4 __attribute__((ext_vector_type(4)));

// ---------------------------------------------------------------------------
// Kernel 1: per-column weight  w[b] = (sum_j [attr==1]*total/num_j) * (sum_j 1-cos(ea_j))
// ---------------------------------------------------------------------------
__global__ __launch_bounds__(NTHREADS) void weight_kernel(
    const float4* __restrict__ ea,        // [3][B/4]
    const int4*   __restrict__ attr,      // [6][B/4]
    const float*  __restrict__ attr_num,  // [6]
    float4*       __restrict__ weight)    // [B/4]
{
    int cq = blockIdx.x * blockDim.x + threadIdx.x;
    if (cq >= CQ_TOTAL) return;

    float total = attr_num[0] + attr_num[1] + attr_num[2] +
                  attr_num[3] + attr_num[4] + attr_num[5];

    float aw[4] = {0.f, 0.f, 0.f, 0.f};
#pragma unroll
    for (int j = 0; j < 6; ++j) {
        int4 a = attr[j * CQ_TOTAL + cq];
        float f = total / attr_num[j];
        aw[0] += (a.x == 1) ? f : 0.f;
        aw[1] += (a.y == 1) ? f : 0.f;
        aw[2] += (a.z == 1) ? f : 0.f;
        aw[3] += (a.w == 1) ? f : 0.f;
    }

    float angw[4] = {0.f, 0.f, 0.f, 0.f};
#pragma unroll
    for (int j = 0; j < 3; ++j) {
        float4 e = ea[j * CQ_TOTAL + cq];
        angw[0] += 1.f - cosf(e.x);
        angw[1] += 1.f - cosf(e.y);
        angw[2] += 1.f - cosf(e.z);
        angw[3] += 1.f - cosf(e.w);
    }

    float4 w;
    w.x = aw[0] * angw[0];
    w.y = aw[1] * angw[1];
    w.z = aw[2] * angw[2];
    w.w = aw[3] * angw[3];
    weight[cq] = w;
}

// ---------------------------------------------------------------------------
// Kernel 2: each thread owns one column-quad x 8 rows. All 17 16-B loads are
// issued as volatile inline asm (SGPR base + u32 voffset; arrays are 71 MB so
// 32-bit offsets are exact), then ONE s_waitcnt vmcnt(0) + sched_barrier(0).
// Volatile asm cannot be sunk by the scheduler -> 17 loads genuinely in
// flight per thread (the "memory"-clobber attempt in R3/R4 did not do this;
// VGPR_Count=36 proved it).
// ---------------------------------------------------------------------------
__global__ __launch_bounds__(NTHREADS) void mse_kernel(
    const float* __restrict__ inp,
    const float* __restrict__ label,
    const float* __restrict__ weight,
    double*      __restrict__ partials)
{
    const int cq = blockIdx.x * blockDim.x + threadIdx.x;     // 0..32767
    const unsigned int row0   = blockIdx.y * ROWS_PER_CHUNK;
    const unsigned int off0   = (row0 * CQ_TOTAL + (unsigned int)cq) * 16u;
    const unsigned int offw   = (unsigned int)cq * 16u;
    const unsigned int rstride = CQ_TOTAL * 16u;              // 512 KiB

    f4 w, av[ROWS_PER_CHUNK], lv[ROWS_PER_CHUNK];

    asm volatile("global_load_dwordx4 %0, %1, %2"
                 : "=v"(w) : "v"(offw), "s"(weight));
#pragma unroll
    for (int r = 0; r < ROWS_PER_CHUNK; ++r) {
        unsigned int o = off0 + (unsigned int)r * rstride;
        asm volatile("global_load_dwordx4 %0, %1, %2"
                     : "=v"(av[r]) : "v"(o), "s"(inp));
    }
#pragma unroll
    for (int r = 0; r < ROWS_PER_CHUNK; ++r) {
        unsigned int o = off0 + (unsigned int)r * rstride;
        asm volatile("global_load_dwordx4 %0, %1, %2"
                     : "=v"(lv[r]) : "v"(o), "s"(label));
    }

    asm volatile("s_waitcnt vmcnt(0)" ::: "memory");
    __builtin_amdgcn_sched_barrier(0);   // keep uses below the waitcnt

    float acc = 0.f;
#pragma unroll
    for (int r = 0; r < ROWS_PER_CHUNK; ++r) {
        f4 d = av[r] - lv[r];
        f4 p = w * d * d;
        acc += (p.x + p.y) + (p.z + p.w);
    }

    // 64-lane wave shuffle reduce
    for (int off = 32; off > 0; off >>= 1)
        acc += __shfl_down(acc, off, 64);

    __shared__ double sw[NTHREADS / 64];
    int lane = threadIdx.x & 63;
    int wid  = threadIdx.x >> 6;
    if (lane == 0) sw[wid] = (double)acc;
    __syncthreads();
    if (threadIdx.x == 0) {
        double s = sw[0] + sw[1] + sw[2] + sw[3];
        partials[blockIdx.y * gridDim.x + blockIdx.x] = s;
    }
}

// ---------------------------------------------------------------------------
// Kernel 3: final reduce of block partials -> mean
// ---------------------------------------------------------------------------
__global__ __launch_bounds__(NTHREADS) void final_kernel(
    const double* __restrict__ partials,
    int n,
    float* __restrict__ out)
{
    double acc = 0.0;
    for (int i = threadIdx.x; i < n; i += blockDim.x) acc += partials[i];

    for (int off = 32; off > 0; off >>= 1)
        acc += __shfl_down(acc, off, 64);

    __shared__ double sw[NTHREADS / 64];
    int lane = threadIdx.x & 63;
    int wid  = threadIdx.x >> 6;
    if (lane == 0) sw[wid] = acc;
    __syncthreads();
    if (threadIdx.x == 0) {
        double s = 0.0;
#pragma unroll
        for (int v = 0; v < NTHREADS / 64; ++v) s += sw[v];
        out[0] = (float)(s / ((double)D_ROWS * (double)B_COLS));
    }
}

// ---------------------------------------------------------------------------
extern "C" void kernel_launch(void* const* d_in, const int* in_sizes, int n_in,
                              void* d_out, int out_size, void* d_ws, size_t ws_size,
                              hipStream_t stream) {
    const float* inp      = (const float*)d_in[0];   // [D][B]
    const float* label    = (const float*)d_in[1];   // [D][B]
    const float* ea       = (const float*)d_in[2];   // [3][B]
    const int*   attr     = (const int*)d_in[3];     // [6][B]
    const float* attr_num = (const float*)d_in[4];   // [6]
    float* out = (float*)d_out;

    // ws layout: weight [B] floats, then partials [NPARTIALS] doubles
    float*  weight   = (float*)d_ws;
    double* partials = (double*)((char*)d_ws + (size_t)B_COLS * sizeof(float));

    weight_kernel<<<CQ_TOTAL / NTHREADS, NTHREADS, 0, stream>>>(
        (const float4*)ea, (const int4*)attr, attr_num, (float4*)weight);

    mse_kernel<<<dim3(CQ_BLOCKS, ROW_CHUNKS), NTHREADS, 0, stream>>>(
        inp, label, weight, partials);

    final_kernel<<<1, NTHREADS, 0, stream>>>(partials, NPARTIALS, out);
}